// Round 6
// baseline (249.858 us; speedup 1.0000x reference)
//
#include <hip/hip_runtime.h>
#include <math.h>

#define NB 4096
#define PAD 2048
#define TPB 1024          // 16 waves per block
#define WPB 16            // waves (rows) per block

typedef float f32x4 __attribute__((ext_vector_type(4)));

__device__ __forceinline__ int mirror_idx(int i) {
    // valid for i in [-PAD, NB+PAD-2]; single reflection
    i = ::abs(i);
    return (i < NB) ? i : (2 * (NB - 1) - i);
}

// Precompute p = sigmoid(logits), lsp = log_sigmoid(logits), lsn = log_sigmoid(-logits)
__global__ void fbmp_precompute(const float* __restrict__ logits, float* __restrict__ ws) {
    int j = blockIdx.x * blockDim.x + threadIdx.x;
    if (j >= NB) return;
    float x = logits[j];
    double xd = (double)x;
    float e = (float)exp(-xd);
    float p = 1.0f / (1.0f + e);
    float lsp = (float)(-log1p(exp(-xd)));  // log_sigmoid(x)
    float lsn = (float)(-log1p(exp(xd)));   // log_sigmoid(-x)
    ws[j] = p;
    ws[NB + j] = lsp;
    ws[2 * NB + j] = lsn;
}

// ---- wave-per-row kernel: no barriers after table staging ----
// Row's 4096 grid bits transposed into 64 u64 words via __ballot; lane l owns
// word l (elements j = 256c + 4*l' + q live in word 4c+q, bit l').
// logp is bit-exact vs the verified kernel: lane l group c == original thread
// 64*(c&3)+l group c>>2; four accumulators + identical shuffle tree + identical
// final summation order.
__global__ __launch_bounds__(TPB, 4) void fbmp_wave(
    const float* __restrict__ u, const int* __restrict__ shift,
    const float* __restrict__ ws,
    float* __restrict__ masks, float* __restrict__ logp, int B)
{
    __shared__ float tbl[3 * NB];                    // 48 KB: p, lsp, lsn
    __shared__ unsigned long long words[WPB][64];    // 8 KB: per-wave bit rows

    const int t = threadIdx.x;

    // stage tables once per block (3 float4 per thread)
    {
        const float4* __restrict__ src = (const float4*)ws;
        float4* __restrict__ dst = (float4*)tbl;
        #pragma unroll
        for (int c = 0; c < (3 * NB / 4) / TPB; ++c)
            dst[t + c * TPB] = src[t + c * TPB];
    }
    __syncthreads();   // the ONLY barrier

    const int lane = t & 63;
    const int wid  = t >> 6;
    const int row  = blockIdx.x * WPB + wid;
    if (row >= B) return;                            // wave-uniform

    const int s = shift[row] - PAD;                  // wave-uniform scalar load
    const float4* __restrict__ u4   = (const float4*)(u + (size_t)row * NB);
    const float4* __restrict__ p4   = (const float4*)tbl;
    const float4* __restrict__ lsp4 = (const float4*)(tbl + NB);
    const float4* __restrict__ lsn4 = (const float4*)(tbl + 2 * NB);

    float accw[4] = {0.0f, 0.0f, 0.0f, 0.0f};
    unsigned long long myword = 0ull;

    #pragma unroll
    for (int c = 0; c < 16; ++c) {
        const int i = lane + 64 * c;                 // float4 index
        float4 uv = u4[i];
        float4 pv = p4[i];
        float4 ap = lsp4[i];
        float4 an = lsn4[i];
        bool c0 = uv.x < pv.x;
        bool c1 = uv.y < pv.y;
        bool c2 = uv.z < pv.z;
        bool c3 = uv.w < pv.w;
        // identical quad association as the verified kernel
        accw[c & 3] += (c0 ? ap.x : an.x) + (c1 ? ap.y : an.y)
                     + (c2 ? ap.z : an.z) + (c3 ? ap.w : an.w);
        unsigned long long b0 = __ballot(c0);
        unsigned long long b1 = __ballot(c1);
        unsigned long long b2 = __ballot(c2);
        unsigned long long b3 = __ballot(c3);
        if ((lane >> 2) == c) {                      // lane owns word64 #lane
            unsigned long long m0 = (lane & 1) ? b1 : b0;
            unsigned long long m1 = (lane & 1) ? b3 : b2;
            myword = (lane & 2) ? m1 : m0;
        }
    }
    words[wid][lane] = myword;                       // wave-private; no barrier

    // logp: per-original-wave tree reductions (identical shfl pattern), then
    // identical sred[0..3] summation order
    #pragma unroll
    for (int w = 0; w < 4; ++w) {
        #pragma unroll
        for (int off = 32; off > 0; off >>= 1)
            accw[w] += __shfl_down(accw[w], off, 64);
    }
    if (lane == 0) {
        float tt = 0.0f;
        tt += accw[0];
        tt += accw[1];
        tt += accw[2];
        tt += accw[3];
        logp[row] = tt;
    }

    // gather + wide NT store. Word index per ds_read is lane-uniform
    // (j = 4*lane' + const → j&3 and j>>8 uniform) → broadcast, conflict-free.
    const unsigned int* __restrict__ w32 = (const unsigned int*)&words[wid][0];
    float* __restrict__ mrow = masks + (size_t)row * NB;
    #pragma unroll
    for (int c = 0; c < 16; ++c) {
        const int i = lane + 64 * c;
        const int k = 4 * i + s;
        f32x4 o;
        {
            const int j = mirror_idx(k + 0);
            const int w64 = ((j >> 8) << 2) | (j & 3);
            const int bit = (j >> 2) & 63;
            o.x = ((w32[(w64 << 1) | (bit >> 5)] >> (bit & 31)) & 1u) ? 1.0f : 0.0f;
        }
        {
            const int j = mirror_idx(k + 1);
            const int w64 = ((j >> 8) << 2) | (j & 3);
            const int bit = (j >> 2) & 63;
            o.y = ((w32[(w64 << 1) | (bit >> 5)] >> (bit & 31)) & 1u) ? 1.0f : 0.0f;
        }
        {
            const int j = mirror_idx(k + 2);
            const int w64 = ((j >> 8) << 2) | (j & 3);
            const int bit = (j >> 2) & 63;
            o.z = ((w32[(w64 << 1) | (bit >> 5)] >> (bit & 31)) & 1u) ? 1.0f : 0.0f;
        }
        {
            const int j = mirror_idx(k + 3);
            const int w64 = ((j >> 8) << 2) | (j & 3);
            const int bit = (j >> 2) & 63;
            o.w = ((w32[(w64 << 1) | (bit >> 5)] >> (bit & 31)) & 1u) ? 1.0f : 0.0f;
        }
        __builtin_nontemporal_store(o, (f32x4*)mrow + i);
    }
}

extern "C" void kernel_launch(void* const* d_in, const int* in_sizes, int n_in,
                              void* d_out, int out_size, void* d_ws, size_t ws_size,
                              hipStream_t stream) {
    const float* logits = (const float*)d_in[0];
    const float* u      = (const float*)d_in[1];
    const int*   shift  = (const int*)d_in[2];
    const int B = in_sizes[2];

    float* ws    = (float*)d_ws;                    // 3*NB floats (tables)
    float* masks = (float*)d_out;                   // B*NB
    float* logp  = (float*)d_out + (size_t)B * NB;  // B

    fbmp_precompute<<<(NB + 255) / 256, 256, 0, stream>>>(logits, ws);
    const int grid = (B + WPB - 1) / WPB;
    fbmp_wave<<<grid, TPB, 0, stream>>>(u, shift, ws, masks, logp, B);
}

// Round 7
// 242.068 us; speedup vs baseline: 1.0322x; 1.0322x over previous
//
#include <hip/hip_runtime.h>
#include <math.h>

#define NB 4096
#define PAD 2048

typedef float f32x4 __attribute__((ext_vector_type(4)));

__device__ __forceinline__ int mirror_idx(int i) {
    // valid for i in [-PAD, NB+PAD-2]; single reflection
    i = ::abs(i);
    return (i < NB) ? i : (2 * (NB - 1) - i);
}

// Precompute p = sigmoid(logits), lsp = log_sigmoid(logits), lsn = log_sigmoid(-logits)
__global__ void fbmp_precompute(const float* __restrict__ logits, float* __restrict__ ws) {
    int j = blockIdx.x * blockDim.x + threadIdx.x;
    if (j >= NB) return;
    float x = logits[j];
    double xd = (double)x;
    float e = (float)exp(-xd);
    float p = 1.0f / (1.0f + e);
    float lsp = (float)(-log1p(exp(-xd)));  // log_sigmoid(x)
    float lsn = (float)(-log1p(exp(xd)));   // log_sigmoid(-x)
    ws[j] = p;
    ws[NB + j] = lsp;
    ws[2 * NB + j] = lsn;
}

// ---------------- Kernel A: pure read stream (wave per row) ----------------
// All 16 u-float4 loads issued before any use (256 B/lane MLP). Tables from
// global (chip-hot in L1/L2). Emits packed grid bits (512 B/row) + logp.
// logp is bit-exact vs the verified kernel (see round-6 mapping: lane l,
// group c == original thread 64*(c&3)+l, group c>>2).
__global__ __launch_bounds__(256, 4) void fbmp_bits(
    const float* __restrict__ u, const float* __restrict__ ws,
    unsigned long long* __restrict__ pb, float* __restrict__ logp, int B)
{
    const int t = threadIdx.x;
    const int lane = t & 63;
    const int wid  = t >> 6;
    const int row  = blockIdx.x * 4 + wid;
    if (row >= B) return;                         // wave-uniform

    const float4* __restrict__ u4   = (const float4*)(u + (size_t)row * NB);
    const float4* __restrict__ p4   = (const float4*)(ws);
    const float4* __restrict__ lsp4 = (const float4*)(ws + NB);
    const float4* __restrict__ lsn4 = (const float4*)(ws + 2 * NB);

    // stage the whole row: 16 independent dwordx4 loads in flight
    float4 uvv[16];
    #pragma unroll
    for (int c = 0; c < 16; ++c) uvv[c] = u4[lane + 64 * c];

    float accw[4] = {0.0f, 0.0f, 0.0f, 0.0f};
    unsigned long long myword = 0ull;

    #pragma unroll
    for (int c = 0; c < 16; ++c) {
        const int i = lane + 64 * c;
        float4 pv = p4[i];
        float4 ap = lsp4[i];
        float4 an = lsn4[i];
        bool c0 = uvv[c].x < pv.x;
        bool c1 = uvv[c].y < pv.y;
        bool c2 = uvv[c].z < pv.z;
        bool c3 = uvv[c].w < pv.w;
        // identical quad association as the verified kernel
        accw[c & 3] += (c0 ? ap.x : an.x) + (c1 ? ap.y : an.y)
                     + (c2 ? ap.z : an.z) + (c3 ? ap.w : an.w);
        unsigned long long b0 = __ballot(c0);
        unsigned long long b1 = __ballot(c1);
        unsigned long long b2 = __ballot(c2);
        unsigned long long b3 = __ballot(c3);
        if ((lane >> 2) == c) {                   // lane owns u64 word #lane
            unsigned long long m0 = (lane & 1) ? b1 : b0;
            unsigned long long m1 = (lane & 1) ? b3 : b2;
            myword = (lane & 2) ? m1 : m0;
        }
    }

    pb[(size_t)row * 64 + lane] = myword;         // 512 B coalesced per wave

    // logp: per-original-wave shuffle trees + identical final summation order
    #pragma unroll
    for (int w = 0; w < 4; ++w) {
        #pragma unroll
        for (int off = 32; off > 0; off >>= 1)
            accw[w] += __shfl_down(accw[w], off, 64);
    }
    if (lane == 0) {
        float tt = 0.0f;
        tt += accw[0];
        tt += accw[1];
        tt += accw[2];
        tt += accw[3];
        logp[row] = tt;
    }
}

// ---------------- Kernel B: pure write stream (wave per row) ----------------
// Reads 512 B of packed bits (L2-hot), expands via wave-private LDS broadcast
// (lane-uniform word index per access -> conflict-free), fires 16 NT dwordx4
// stores back-to-back. No block barriers (wave-synchronous LDS use, same
// pattern as the verified round-6 kernel).
__global__ __launch_bounds__(256, 8) void fbmp_masks(
    const unsigned long long* __restrict__ pb, const int* __restrict__ shift,
    float* __restrict__ masks, int B)
{
    __shared__ unsigned long long words[4][64];   // per-wave bit rows (2 KB)

    const int t = threadIdx.x;
    const int lane = t & 63;
    const int wid  = t >> 6;
    const int row  = blockIdx.x * 4 + wid;
    if (row >= B) return;                         // wave-uniform

    words[wid][lane] = pb[(size_t)row * 64 + lane];
    const int s = shift[row] - PAD;               // wave-uniform

    const unsigned int* __restrict__ w32 = (const unsigned int*)&words[wid][0];
    float* __restrict__ mrow = masks + (size_t)row * NB;

    #pragma unroll
    for (int c = 0; c < 16; ++c) {
        const int i = lane + 64 * c;
        const int k = 4 * i + s;
        f32x4 o;
        {
            const int j = mirror_idx(k + 0);
            const int w64 = ((j >> 8) << 2) | (j & 3);
            const int bit = (j >> 2) & 63;
            o.x = ((w32[(w64 << 1) | (bit >> 5)] >> (bit & 31)) & 1u) ? 1.0f : 0.0f;
        }
        {
            const int j = mirror_idx(k + 1);
            const int w64 = ((j >> 8) << 2) | (j & 3);
            const int bit = (j >> 2) & 63;
            o.y = ((w32[(w64 << 1) | (bit >> 5)] >> (bit & 31)) & 1u) ? 1.0f : 0.0f;
        }
        {
            const int j = mirror_idx(k + 2);
            const int w64 = ((j >> 8) << 2) | (j & 3);
            const int bit = (j >> 2) & 63;
            o.z = ((w32[(w64 << 1) | (bit >> 5)] >> (bit & 31)) & 1u) ? 1.0f : 0.0f;
        }
        {
            const int j = mirror_idx(k + 3);
            const int w64 = ((j >> 8) << 2) | (j & 3);
            const int bit = (j >> 2) & 63;
            o.w = ((w32[(w64 << 1) | (bit >> 5)] >> (bit & 31)) & 1u) ? 1.0f : 0.0f;
        }
        __builtin_nontemporal_store(o, (f32x4*)mrow + i);
    }
}

// ---------------- Fallback: round-0 fused kernel (proven) ----------------
__global__ __launch_bounds__(256) void fbmp_fused(
    const float* __restrict__ u, const int* __restrict__ shift,
    const float* __restrict__ ws,
    float* __restrict__ masks, float* __restrict__ logp)
{
    __shared__ float sg[NB];
    __shared__ float sred[4];

    const int b = blockIdx.x;
    const float4* __restrict__ u4   = (const float4*)(u + (size_t)b * NB);
    const float4* __restrict__ p4   = (const float4*)(ws);
    const float4* __restrict__ lsp4 = (const float4*)(ws + NB);
    const float4* __restrict__ lsn4 = (const float4*)(ws + 2 * NB);

    float acc = 0.0f;
    for (int i = threadIdx.x; i < NB / 4; i += 256) {
        float4 uv = u4[i];
        float4 pv = p4[i];
        float4 ap = lsp4[i];
        float4 an = lsn4[i];
        bool c0 = uv.x < pv.x;
        bool c1 = uv.y < pv.y;
        bool c2 = uv.z < pv.z;
        bool c3 = uv.w < pv.w;
        acc += (c0 ? ap.x : an.x) + (c1 ? ap.y : an.y)
             + (c2 ? ap.z : an.z) + (c3 ? ap.w : an.w);
        float4 g;
        g.x = c0 ? 1.0f : 0.0f;
        g.y = c1 ? 1.0f : 0.0f;
        g.z = c2 ? 1.0f : 0.0f;
        g.w = c3 ? 1.0f : 0.0f;
        ((float4*)sg)[i] = g;
    }
    #pragma unroll
    for (int off = 32; off > 0; off >>= 1)
        acc += __shfl_down(acc, off, 64);
    const int lane = threadIdx.x & 63;
    const int wid  = threadIdx.x >> 6;
    if (lane == 0) sred[wid] = acc;
    __syncthreads();
    if (threadIdx.x == 0) {
        float t = 0.0f;
        #pragma unroll
        for (int w = 0; w < 4; ++w) t += sred[w];
        logp[b] = t;
    }
    const int s = shift[b] - PAD;
    float4* __restrict__ m4 = (float4*)(masks + (size_t)b * NB);
    for (int i = threadIdx.x; i < NB / 4; i += 256) {
        int k = 4 * i + s;
        float4 o;
        o.x = sg[mirror_idx(k + 0)];
        o.y = sg[mirror_idx(k + 1)];
        o.z = sg[mirror_idx(k + 2)];
        o.w = sg[mirror_idx(k + 3)];
        m4[i] = o;
    }
}

extern "C" void kernel_launch(void* const* d_in, const int* in_sizes, int n_in,
                              void* d_out, int out_size, void* d_ws, size_t ws_size,
                              hipStream_t stream) {
    const float* logits = (const float*)d_in[0];
    const float* u      = (const float*)d_in[1];
    const int*   shift  = (const int*)d_in[2];
    const int B = in_sizes[2];

    float* ws    = (float*)d_ws;                    // 3*NB floats (tables)
    float* masks = (float*)d_out;                   // B*NB
    float* logp  = (float*)d_out + (size_t)B * NB;  // B

    fbmp_precompute<<<(NB + 255) / 256, 256, 0, stream>>>(logits, ws);

    const size_t tbl_bytes = (size_t)3 * NB * sizeof(float);                  // 48 KB
    const size_t pb_bytes  = (size_t)B * 64 * sizeof(unsigned long long);     // 4 MB
    if (ws_size >= tbl_bytes + pb_bytes) {
        unsigned long long* pb = (unsigned long long*)((char*)d_ws + tbl_bytes);
        const int grid = (B + 3) / 4;
        fbmp_bits <<<grid, 256, 0, stream>>>(u, ws, pb, logp, B);
        fbmp_masks<<<grid, 256, 0, stream>>>(pb, shift, masks, B);
    } else {
        fbmp_fused<<<B, 256, 0, stream>>>(u, shift, ws, masks, logp);
    }
}